// Round 2
// baseline (3718.480 us; speedup 1.0000x reference)
//
#include <hip/hip_runtime.h>
#include <cstdint>
#include <cstddef>

// ---------------------------------------------------------------------------
// QLSTM: LSTM scan (recurrence) + batch-axis attention quirk, all-f16 internal.
// Pipeline: prep (weight transposes/swizzles) -> cvt_x -> GEMM xproj ->
//           scan (64 WGs, VGPR+LDS-resident recurrent weights) ->
//           GEMM qkv -> fused per-(s,h) attention -> GEMM out_proj (+Hseq add)
// ws map (bytes):
//   [0, 134217728)          Xp f16 [1024][64][1024]   (later reused: qkv at 0,
//                           ctx at 100663296 — Xp dead after scan)
//   [134217728, +33554432)  Xh f16 [65536][256]
//   [167772160, +33554432)  Hseq_h f16 [65536][256]
//   [201326592, +524288)    W_scan f16 [1024 cols][256 k]  (hx rows of gates)
//   [201850880, +524288)    Wxt frag-major f16 (N=1024,K=256)
//   [202375168, +393216)    in_proj frag-major f16 (N=768,K=256)
//   [202768384, +131072)    out_proj frag-major f16 (N=256,K=256)
//   [202899456, +4096)      bias4 f32 [1024]
// Total ws: ~193.5 MiB.
//
// R2 change: scan_k restructured for register-file fit + occupancy.
//  R1 evidence: VGPR_Count=128 with a 192-reg weight array => compiler split
//  128 arch + ~128 AGPR; v_dot2 can't read AGPRs so each AGPR-resident weight
//  use paid a v_accvgpr_read (~1500 parasitic VALU cyc/step), and 2 waves/SIMD
//  couldn't hide LDS/barrier/update latency (step 5497 cyc vs 1024 essential).
//  Now: 1024 thr/WG (16 waves, 4/SIMD, hard 128-VGPR cap), ONE column/thread,
//  96 weight k-pairs in VGPRs + 32 k-pairs in LDS (128 KB) read as swizzled
//  conflict-free ds_read_b128. rcp-based sigmoid/tanh. Same math per column.
// ---------------------------------------------------------------------------

typedef _Float16 f16;
typedef __attribute__((ext_vector_type(2))) _Float16 half2v;
typedef __attribute__((ext_vector_type(4))) _Float16 half4v;
typedef __attribute__((ext_vector_type(8))) _Float16 half8v;
typedef __attribute__((ext_vector_type(4))) float   float4v;
typedef __attribute__((ext_vector_type(2))) float   float2v;
typedef __attribute__((ext_vector_type(4))) unsigned uint4v;

static __device__ __forceinline__ half2v u2h(unsigned u) {
  union { unsigned u; half2v h; } x; x.u = u; return x.h;
}
static __device__ __forceinline__ float rcp_fast(float x) {
  return __builtin_amdgcn_rcpf(x);
}
static __device__ __forceinline__ float sigm(float x) {
  return rcp_fast(1.0f + __expf(-x));
}
static __device__ __forceinline__ float tanh_fast(float x) {
  x = fminf(15.0f, fmaxf(-15.0f, x));
  float e = __expf(2.0f * x);
  return (e - 1.0f) * rcp_fast(e + 1.0f);
}
static __device__ __forceinline__ const float* selW(int g, const float* a, const float* b,
                                                    const float* c, const float* d) {
  return g == 0 ? a : (g == 1 ? b : (g == 2 ? c : d));
}

// Workgroup barrier that orders LDS only: does NOT drain vmcnt, so global
// loads (read-only Xp) and stores (write-only dout/Hh) stay in flight.
static __device__ __forceinline__ void wg_barrier_lds() {
  __builtin_amdgcn_sched_barrier(0);
  asm volatile("s_waitcnt lgkmcnt(0)" ::: "memory");
  __builtin_amdgcn_s_barrier();
  __builtin_amdgcn_sched_barrier(0);
}

// ---------------------------------------------------------------------------
// prep: build f16 weight layouts.
//  seg0: W_scan[c][k] = W_g[(256+k)*256 + j]        (c = g*256+j, k=0..255)
//  seg1: Wxt frag-major, N=1024: elem e -> (ntile,kstep,lane,j); value W_g[k][j]
//  seg2: in_proj frag-major, N=768
//  seg3: out_proj frag-major, N=256
//  seg4: bias4[c] = b_g[j]
// frag-major B layout: flat = ((ntile*8 + kstep)*64 + lane)*8 + j ;
//   n = ntile*16 + (lane&15); k = kstep*32 + ((lane>>4)&3)*8 + j
// ---------------------------------------------------------------------------
__global__ void prep_k(const float* __restrict__ Wf, const float* __restrict__ Wi,
                       const float* __restrict__ Wg_, const float* __restrict__ Wo,
                       const float* __restrict__ bf, const float* __restrict__ bi,
                       const float* __restrict__ bg_, const float* __restrict__ bo,
                       const float* __restrict__ inpw, const float* __restrict__ outpw,
                       f16* __restrict__ wscan, f16* __restrict__ wxt,
                       f16* __restrict__ inpj, f16* __restrict__ outpj,
                       float* __restrict__ bias4)
{
  const int total = 262144 + 262144 + 196608 + 65536 + 1024;
  for (int e = blockIdx.x * blockDim.x + threadIdx.x; e < total; e += gridDim.x * blockDim.x) {
    int x = e;
    if (x < 262144) {                 // W_scan [c][k]
      int c = x >> 8, k = x & 255;
      int g = c >> 8, j = c & 255;
      const float* W = selW(g, Wf, Wi, Wg_, Wo);
      wscan[x] = (f16)W[(256 + k) * 256 + j];
      continue;
    }
    x -= 262144;
    if (x < 262144) {                 // Wxt frag-major (N=1024)
      int j = x & 7, lane = (x >> 3) & 63, kstep = (x >> 9) & 7, ntile = x >> 12;
      int n = ntile * 16 + (lane & 15);
      int k = kstep * 32 + ((lane >> 4) & 3) * 8 + j;
      int g = n >> 8, jj = n & 255;
      const float* W = selW(g, Wf, Wi, Wg_, Wo);
      wxt[x] = (f16)W[k * 256 + jj];
      continue;
    }
    x -= 262144;
    if (x < 196608) {                 // in_proj frag-major (N=768)
      int j = x & 7, lane = (x >> 3) & 63, kstep = (x >> 9) & 7, ntile = x >> 12;
      int n = ntile * 16 + (lane & 15);
      int k = kstep * 32 + ((lane >> 4) & 3) * 8 + j;
      inpj[x] = (f16)inpw[k * 768 + n];
      continue;
    }
    x -= 196608;
    if (x < 65536) {                  // out_proj frag-major (N=256)
      int j = x & 7, lane = (x >> 3) & 63, kstep = (x >> 9) & 7, ntile = x >> 12;
      int n = ntile * 16 + (lane & 15);
      int k = kstep * 32 + ((lane >> 4) & 3) * 8 + j;
      outpj[x] = (f16)outpw[k * 256 + n];
      continue;
    }
    x -= 65536;
    {                                 // bias4
      int g = x >> 8, j = x & 255;
      const float* bp = selW(g, bf, bi, bg_, bo);
      bias4[x] = bp[j];
    }
  }
}

// ---------------------------------------------------------------------------
__global__ void cvt_x_k(const float4v* __restrict__ X, half4v* __restrict__ Xh)
{
  int i = blockIdx.x * 256 + threadIdx.x;   // grid sized exactly: 16777216/4
  float4v v = X[i];
  half4v h;
  h.x = (f16)v.x; h.y = (f16)v.y; h.z = (f16)v.z; h.w = (f16)v.w;
  Xh[i] = h;
}

// ---------------------------------------------------------------------------
// Generic MFMA GEMM: C[65536][NTOT] = A[65536][256](f16) @ Bfrag(N=NTOT,K=256)
// + bias[n].  OUT_EPI=false: store f16 to Oh.  OUT_EPI=true: Of += (f32).
// Block 256 thr (4 waves, 2x2 wave grid), tile 128x128, K chunks of 64.
// ---------------------------------------------------------------------------
template<int NTOT, bool OUT_EPI>
__global__ __launch_bounds__(256, 2) void gemm_k(const f16* __restrict__ A,
    const f16* __restrict__ Bf, const float* __restrict__ bias,
    f16* __restrict__ Oh, float* __restrict__ Of)
{
  __shared__ f16 Al[8192];            // [8 mtiles][2 ksteps][64 lanes][8]
  const int tid = threadIdx.x;
  const int lane = tid & 63;
  const int wm = (tid >> 7) & 1;
  const int wn = (tid >> 6) & 1;
  const int m0 = blockIdx.y * 128, n0 = blockIdx.x * 128;

  float4v acc[4][4];
  #pragma unroll
  for (int i = 0; i < 4; ++i)
    #pragma unroll
    for (int j = 0; j < 4; ++j) { acc[i][j].x = 0.f; acc[i][j].y = 0.f; acc[i][j].z = 0.f; acc[i][j].w = 0.f; }

  #pragma unroll 1
  for (int kc = 0; kc < 4; ++kc) {
    __syncthreads();
    #pragma unroll
    for (int p = 0; p < 4; ++p) {
      int m = p * 32 + (tid >> 3);
      int kk = (tid & 7) * 8;
      half8v v = *(const half8v*)(A + (size_t)(m0 + m) * 256 + kc * 64 + kk);
      int lt = ((kk >> 3) & 3) * 16 + (m & 15);
      *(half8v*)(Al + (((m >> 4) * 2 + (kk >> 5)) * 64 + lt) * 8) = v;
    }
    __syncthreads();
    half8v bfr[4][2], afr[4][2];
    #pragma unroll
    for (int i = 0; i < 4; ++i) {
      int NT = (n0 >> 4) + wn * 4 + i;
      #pragma unroll
      for (int ks = 0; ks < 2; ++ks)
        bfr[i][ks] = *(const half8v*)(Bf + (size_t)((NT * 8 + kc * 2 + ks) * 64 + lane) * 8);
    }
    #pragma unroll
    for (int i = 0; i < 4; ++i) {
      int MT = wm * 4 + i;
      #pragma unroll
      for (int ks = 0; ks < 2; ++ks)
        afr[i][ks] = *(const half8v*)(Al + ((MT * 2 + ks) * 64 + lane) * 8);
    }
    #pragma unroll
    for (int ks = 0; ks < 2; ++ks)
      #pragma unroll
      for (int i = 0; i < 4; ++i)
        #pragma unroll
        for (int jn = 0; jn < 4; ++jn)
          acc[i][jn] = __builtin_amdgcn_mfma_f32_16x16x32_f16(afr[i][ks], bfr[jn][ks], acc[i][jn], 0, 0, 0);
  }

  const int r0 = (lane >> 4) * 4, cn = lane & 15;
  #pragma unroll
  for (int i = 0; i < 4; ++i) {
    #pragma unroll
    for (int jn = 0; jn < 4; ++jn) {
      int n = n0 + wn * 64 + jn * 16 + cn;
      float bv = bias[n];
      int mb = m0 + wm * 64 + i * 16 + r0;
      #pragma unroll
      for (int r = 0; r < 4; ++r) {
        float v = acc[i][jn][r] + bv;
        size_t off = (size_t)(mb + r) * NTOT + n;
        if constexpr (OUT_EPI) Of[off] = v + Of[off];
        else                   Oh[off] = (f16)v;
      }
    }
  }
}

// ---------------------------------------------------------------------------
// LSTM scan. 64 WGs (one per batch element) x 1024 threads (16 waves, 4/SIMD).
// Thread t owns ONE gate-column c = t (gate g = t>>8).
// Recurrent weights per column: 128 f16x2 k-pairs. K-pairs 0..95 live in
// VGPRs (96 u32/thread — fits the hard 128-VGPR cap of launch_bounds(1024,4),
// so no AGPR aliasing / v_accvgpr_read parasite). K-pairs 96..127 live in LDS
// (128 KB), stored 4-kpairs-contiguous per column with an XOR column swizzle
// (c ^= (c>>3)&3 on the 16B-slot index) so a wave's 64 ds_read_b128 hit
// distinct bank spans (conflict-free optimal).
// Per step: 1-f16 Xp load (prefetched 1 step ahead) -> 128 fdot2 (2 chains) ->
// nonlin (rcp-based) -> gts[c] -> LDS-only barrier -> tid<256 update cx/hx,
// write Hseq f32+f16 -> LDS-only barrier.
// ---------------------------------------------------------------------------
__global__ __launch_bounds__(1024, 4) void scan_k(const f16* __restrict__ Xp,
    const f16* __restrict__ Wscan, float* __restrict__ dout, f16* __restrict__ Hh)
{
  extern __shared__ unsigned smem[];
  unsigned* wl = smem;                         // [8 q4][1024 c swz][4] = 128 KB
  f16* hxs = (f16*)(smem + 32768);             // [256]
  float* gts = (float*)(smem + 32768 + 128);   // [1024]
  const int tid = threadIdx.x;
  const int b = blockIdx.x;
  const int c = tid;
  const int gate = tid >> 8;                   // wave-uniform
  const unsigned* W32 = (const unsigned*)Wscan;   // [1024 c][128 k-pairs]

  // k-pairs 0..95 -> VGPRs
  unsigned wv[96];
  #pragma unroll
  for (int r = 0; r < 96; ++r) wv[r] = W32[c * 128 + r];

  // k-pairs 96..127 -> LDS, b128-friendly swizzled slots
  const int cs = c ^ ((c >> 3) & 3);           // bijective 16B-slot swizzle
  #pragma unroll
  for (int q4 = 0; q4 < 8; ++q4) {
    uint4v w4 = *(const uint4v*)(W32 + c * 128 + 96 + q4 * 4);
    *(uint4v*)(wl + q4 * 4096 + cs * 4) = w4;
  }
  if (tid < 128) ((unsigned*)hxs)[tid] = 0u;
  float cx = 0.0f, hx_keep = 0.0f;
  __syncthreads();                             // prologue: full barrier is fine

  // Xp element for this (b, c): step stride is 64*1024 f16 = 1<<16.
  const f16* xptr = Xp + (size_t)b * 1024 + c;
  f16 xp_cur = xptr[0];

  #pragma unroll 1
  for (int t = 0; t < 1024; ++t) {
    // Prefetch next step's x-projection; latency hides under this step's dots.
    f16 xp_nxt = (f16)0.0f;
    if (t + 1 < 1024) xp_nxt = xptr[(size_t)(t + 1) << 16];

    float a0 = 0.0f, a1 = 0.0f;
    #pragma unroll
    for (int ch = 0; ch < 24; ++ch) {          // VGPR k-pairs 0..95
      half8v h8 = *(const half8v*)(hxs + ch * 8);
      const half2v* hp = (const half2v*)&h8;
      a0 = __builtin_amdgcn_fdot2(hp[0], u2h(wv[ch * 4 + 0]), a0, false);
      a1 = __builtin_amdgcn_fdot2(hp[1], u2h(wv[ch * 4 + 1]), a1, false);
      a0 = __builtin_amdgcn_fdot2(hp[2], u2h(wv[ch * 4 + 2]), a0, false);
      a1 = __builtin_amdgcn_fdot2(hp[3], u2h(wv[ch * 4 + 3]), a1, false);
    }
    #pragma unroll
    for (int q4 = 0; q4 < 8; ++q4) {           // LDS k-pairs 96..127
      half8v h8 = *(const half8v*)(hxs + 192 + q4 * 8);
      const half2v* hp = (const half2v*)&h8;
      uint4v ww = *(const uint4v*)(wl + q4 * 4096 + cs * 4);
      a0 = __builtin_amdgcn_fdot2(hp[0], u2h(ww.x), a0, false);
      a1 = __builtin_amdgcn_fdot2(hp[1], u2h(ww.y), a1, false);
      a0 = __builtin_amdgcn_fdot2(hp[2], u2h(ww.z), a0, false);
      a1 = __builtin_amdgcn_fdot2(hp[3], u2h(ww.w), a1, false);
    }
    float p = (a0 + a1) + (float)xp_cur;
    float v = (gate == 2) ? tanh_fast(p) : sigm(p);
    gts[c] = v;
    wg_barrier_lds();                          // gts visible; no vmcnt drain
    if (tid < 256) {
      float fg = gts[tid], ig = gts[256 + tid], gg = gts[512 + tid], og = gts[768 + tid];
      cx = fg * cx + ig * gg;
      float hv = og * tanh_fast(cx);
      hx_keep = hv;
      hxs[tid] = (f16)hv;
      size_t off = (size_t)(t * 64 + b) * 256 + tid;
      dout[off] = hv;                          // stores stay in flight
      Hh[off] = (f16)hv;
    }
    wg_barrier_lds();                          // hxs visible; no vmcnt drain
    xp_cur = xp_nxt;
  }
  if (tid < 256) {
    dout[(size_t)16777216 + b * 256 + tid] = hx_keep;           // hx
    dout[(size_t)16777216 + 16384 + b * 256 + tid] = cx;        // cx
  }
}

// ---------------------------------------------------------------------------
// Fused batch-axis attention, one WG per (s, head). scores = q.k^T/8 over the
// B=64 axis, softmax, ctx = attn.v. f16 dot2, f32 accum, unnormalized-P trick.
// ---------------------------------------------------------------------------
__global__ __launch_bounds__(256, 2) void attn_k(const f16* __restrict__ qkv,
                                                 f16* __restrict__ ctx)
{
  __shared__ f16 ql[64 * 72];
  __shared__ f16 kl[64 * 72];
  __shared__ f16 vT[64 * 72];     // transposed: [d][k_b]
  __shared__ f16 at[64 * 72];     // exp'd scores (unnormalized), [q_b][k_b]
  __shared__ float sc[64 * 69];
  __shared__ float pmx[256], psm[256], rmx[64], rsm[64];
  const int tid = threadIdx.x;
  const int s = blockIdx.x >> 2, h = blockIdx.x & 3;
  {
    const int bb = tid >> 2, i = tid & 3;
    const f16* base = qkv + (size_t)(s * 64 + bb) * 768 + h * 64 + i * 16;
    half8v q0 = *(const half8v*)(base);
    half8v q1 = *(const half8v*)(base + 8);
    *(half8v*)(ql + bb * 72 + i * 16)     = q0;
    *(half8v*)(ql + bb * 72 + i * 16 + 8) = q1;
    half8v k0 = *(const half8v*)(base + 256);
    half8v k1 = *(const half8v*)(base + 264);
    *(half8v*)(kl + bb * 72 + i * 16)     = k0;
    *(half8v*)(kl + bb * 72 + i * 16 + 8) = k1;
    half8v v0 = *(const half8v*)(base + 512);
    half8v v1 = *(const half8v*)(base + 520);
    #pragma unroll
    for (int z = 0; z < 8; ++z) {
      vT[(i * 16 + z) * 72 + bb]     = v0[z];
      vT[(i * 16 + 8 + z) * 72 + bb] = v1[z];
    }
  }
  __syncthreads();
  {
    const int qb = tid >> 2, g = tid & 3;
    half8v qr[8];
    #pragma unroll
    for (int i = 0; i < 8; ++i) qr[i] = *(const half8v*)(ql + qb * 72 + i * 8);
    #pragma unroll 1
    for (int jj = 0; jj < 16; ++jj) {
      int kb = g + jj * 4;
      float a = 0.0f;
      #pragma unroll
      for (int i = 0; i < 8; ++i) {
        half8v kr = *(const half8v*)(kl + kb * 72 + i * 8);
        const half2v* kp = (const half2v*)&kr;
        const half2v* qp = (const half2v*)&qr[i];
        #pragma unroll
        for (int z = 0; z < 4; ++z) a = __builtin_amdgcn_fdot2(qp[z], kp[z], a, false);
      }
      sc[qb * 69 + kb] = a * 0.125f;
    }
  }
  __syncthreads();
  {
    const int r = tid & 63, q = tid >> 6;
    float m = -1e30f;
    #pragma unroll
    for (int z = 0; z < 16; ++z) m = fmaxf(m, sc[r * 69 + q * 16 + z]);
    pmx[q * 64 + r] = m;
  }
  __syncthreads();
  if (tid < 64)
    rmx[tid] = fmaxf(fmaxf(pmx[tid], pmx[64 + tid]), fmaxf(pmx[128 + tid], pmx[192 + tid]));
  __syncthreads();
  {
    const int r = tid & 63, q = tid >> 6;
    float mx = rmx[r], ssum = 0.0f;
    #pragma unroll
    for (int z = 0; z < 16; ++z) {
      float e = __expf(sc[r * 69 + q * 16 + z] - mx);
      ssum += e;
      at[r * 72 + q * 16 + z] = (f16)e;
    }
    psm[q * 64 + r] = ssum;
  }
  __syncthreads();
  if (tid < 64)
    rsm[tid] = (psm[tid] + psm[64 + tid]) + (psm[128 + tid] + psm[192 + tid]);
  __syncthreads();
  {
    const int qb = tid >> 2, g = tid & 3;
    half8v ar[8];
    #pragma unroll
    for (int i = 0; i < 8; ++i) ar[i] = *(const half8v*)(at + qb * 72 + i * 8);
    const float rinv = 1.0f / rsm[qb];
    f16* outp = ctx + (size_t)(s * 64 + qb) * 256 + h * 64;
    #pragma unroll 1
    for (int z = 0; z < 16; ++z) {
      int d = g + z * 4;
      float a = 0.0f;
      #pragma unroll
      for (int i = 0; i < 8; ++i) {
        half8v vr = *(const half8v*)(vT + d * 72 + i * 8);
        const half2v* vp = (const half2v*)&vr;
        const half2v* ap = (const half2v*)&ar[i];
        #pragma unroll
        for (int zz = 0; zz < 4; ++zz) a = __builtin_amdgcn_fdot2(ap[zz], vp[zz], a, false);
      }
      outp[d] = (f16)(a * rinv);
    }
  }
}

// ---------------------------------------------------------------------------
extern "C" void kernel_launch(void* const* d_in, const int* in_sizes, int n_in,
                              void* d_out, int out_size, void* d_ws, size_t ws_size,
                              hipStream_t stream)
{
  (void)in_sizes; (void)n_in; (void)out_size; (void)ws_size;
  const float* X    = (const float*)d_in[0];
  const float* Wf   = (const float*)d_in[1];
  const float* bf   = (const float*)d_in[2];
  const float* Wi   = (const float*)d_in[3];
  const float* bi   = (const float*)d_in[4];
  const float* Wg   = (const float*)d_in[5];
  const float* bg   = (const float*)d_in[6];
  const float* Wo   = (const float*)d_in[7];
  const float* bo   = (const float*)d_in[8];
  const float* inpw = (const float*)d_in[9];
  const float* inpb = (const float*)d_in[10];
  const float* outpw= (const float*)d_in[11];
  const float* outpb= (const float*)d_in[12];

  char* ws = (char*)d_ws;
  f16*   Xp    = (f16*)(ws + 0);
  f16*   qkv   = (f16*)(ws + 0);                 // reuses Xp region after scan
  f16*   ctxh  = (f16*)(ws + 100663296);         // also inside old Xp region
  f16*   Xh    = (f16*)(ws + 134217728);
  f16*   Hh    = (f16*)(ws + 167772160);
  f16*   wscan = (f16*)(ws + 201326592);
  f16*   wxt   = (f16*)(ws + 201850880);
  f16*   inpj  = (f16*)(ws + 202375168);
  f16*   outpj = (f16*)(ws + 202768384);
  float* bias4 = (float*)(ws + 202899456);
  float* out   = (float*)d_out;

  prep_k<<<1024, 256, 0, stream>>>(Wf, Wi, Wg, Wo, bf, bi, bg, bo, inpw, outpw,
                                   wscan, wxt, inpj, outpj, bias4);
  cvt_x_k<<<16384, 256, 0, stream>>>((const float4v*)X, (half4v*)Xh);
  gemm_k<1024, false><<<dim3(8, 512), 256, 0, stream>>>(Xh, wxt, bias4, Xp, nullptr);
  scan_k<<<64, 1024, 135680, stream>>>(Xp, wscan, out, Hh);
  gemm_k<768, false><<<dim3(6, 512), 256, 0, stream>>>(Hh, inpj, inpb, qkv, nullptr);
  attn_k<<<4096, 256, 0, stream>>>(qkv, ctxh);
  gemm_k<256, true><<<dim3(2, 512), 256, 0, stream>>>(ctxh, outpj, outpb, nullptr, out);
}

// Round 3
// 2464.306 us; speedup vs baseline: 1.5089x; 1.5089x over previous
//
#include <hip/hip_runtime.h>
#include <cstdint>
#include <cstddef>

// ---------------------------------------------------------------------------
// QLSTM: LSTM scan (recurrence) + batch-axis attention quirk, all-f16 internal.
// Pipeline: prep (weight transposes/swizzles) -> cvt_x -> GEMM xproj ->
//           scan (64 WGs, VGPR+LDS-resident recurrent weights) ->
//           GEMM qkv -> fused per-(s,h) attention -> GEMM out_proj (+Hseq add)
// ws map (bytes):
//   [0, 134217728)          Xp f16 [1024][64][1024]   (later reused: qkv at 0,
//                           ctx at 100663296 — Xp dead after scan)
//   [134217728, +33554432)  Xh f16 [65536][256]
//   [167772160, +33554432)  Hseq_h f16 [65536][256]
//   [201326592, +524288)    W_scan f16 [1024 cols][256 k]  (hx rows of gates)
//   [201850880, +524288)    Wxt frag-major f16 (N=1024,K=256)
//   [202375168, +393216)    in_proj frag-major f16 (N=768,K=256)
//   [202768384, +131072)    out_proj frag-major f16 (N=256,K=256)
//   [202899456, +4096)      bias4 f32 [1024]
// Total ws: ~193.5 MiB.
//
// R3 change: register-budget fix via launch_bounds semantics.
//  Evidence: R1 (512,2)->VGPR_Count=128 (weights overflowed to AGPR,
//  v_accvgpr_read parasite); R2 (1024,4)->VGPR_Count=64 (weights spilled to
//  scratch, 2345->3382us). Both match hipcc treating the 2nd launch_bounds arg
//  as min BLOCKS/CU (CUDA semantics): (512,2)=16 waves/CU->128 cap,
//  (1024,4) clamped to 2 blocks=32 waves->64 cap. Grid is 64 WGs on 256 CUs
//  (1 WG/CU always), so multi-block caps are pure loss. (512,1) -> 8 waves/CU
//  -> 256-reg cap: wv[192] + ~55 working fits in arch VGPRs, no AGPR traffic,
//  no spill. Also: 4 independent fdot2 accumulator chains (dep distance 4)
//  to cover VOP3P latency at 2 waves/SIMD.
// ---------------------------------------------------------------------------

typedef _Float16 f16;
typedef __attribute__((ext_vector_type(2))) _Float16 half2v;
typedef __attribute__((ext_vector_type(4))) _Float16 half4v;
typedef __attribute__((ext_vector_type(8))) _Float16 half8v;
typedef __attribute__((ext_vector_type(4))) float   float4v;
typedef __attribute__((ext_vector_type(2))) float   float2v;

static __device__ __forceinline__ half2v u2h(unsigned u) {
  union { unsigned u; half2v h; } x; x.u = u; return x.h;
}
static __device__ __forceinline__ float rcp_fast(float x) {
  return __builtin_amdgcn_rcpf(x);
}
static __device__ __forceinline__ float sigm(float x) {
  return rcp_fast(1.0f + __expf(-x));
}
static __device__ __forceinline__ float tanh_fast(float x) {
  x = fminf(15.0f, fmaxf(-15.0f, x));
  float e = __expf(2.0f * x);
  return (e - 1.0f) * rcp_fast(e + 1.0f);
}
static __device__ __forceinline__ const float* selW(int g, const float* a, const float* b,
                                                    const float* c, const float* d) {
  return g == 0 ? a : (g == 1 ? b : (g == 2 ? c : d));
}

// Workgroup barrier that orders LDS only: does NOT drain vmcnt, so global
// loads (read-only Xp) and stores (write-only dout/Hh) stay in flight.
static __device__ __forceinline__ void wg_barrier_lds() {
  __builtin_amdgcn_sched_barrier(0);
  asm volatile("s_waitcnt lgkmcnt(0)" ::: "memory");
  __builtin_amdgcn_s_barrier();
  __builtin_amdgcn_sched_barrier(0);
}

// ---------------------------------------------------------------------------
// prep: build f16 weight layouts.
//  seg0: W_scan[c][k] = W_g[(256+k)*256 + j]        (c = g*256+j, k=0..255)
//  seg1: Wxt frag-major, N=1024: elem e -> (ntile,kstep,lane,j); value W_g[k][j]
//  seg2: in_proj frag-major, N=768
//  seg3: out_proj frag-major, N=256
//  seg4: bias4[c] = b_g[j]
// frag-major B layout: flat = ((ntile*8 + kstep)*64 + lane)*8 + j ;
//   n = ntile*16 + (lane&15); k = kstep*32 + ((lane>>4)&3)*8 + j
// ---------------------------------------------------------------------------
__global__ void prep_k(const float* __restrict__ Wf, const float* __restrict__ Wi,
                       const float* __restrict__ Wg_, const float* __restrict__ Wo,
                       const float* __restrict__ bf, const float* __restrict__ bi,
                       const float* __restrict__ bg_, const float* __restrict__ bo,
                       const float* __restrict__ inpw, const float* __restrict__ outpw,
                       f16* __restrict__ wscan, f16* __restrict__ wxt,
                       f16* __restrict__ inpj, f16* __restrict__ outpj,
                       float* __restrict__ bias4)
{
  const int total = 262144 + 262144 + 196608 + 65536 + 1024;
  for (int e = blockIdx.x * blockDim.x + threadIdx.x; e < total; e += gridDim.x * blockDim.x) {
    int x = e;
    if (x < 262144) {                 // W_scan [c][k]
      int c = x >> 8, k = x & 255;
      int g = c >> 8, j = c & 255;
      const float* W = selW(g, Wf, Wi, Wg_, Wo);
      wscan[x] = (f16)W[(256 + k) * 256 + j];
      continue;
    }
    x -= 262144;
    if (x < 262144) {                 // Wxt frag-major (N=1024)
      int j = x & 7, lane = (x >> 3) & 63, kstep = (x >> 9) & 7, ntile = x >> 12;
      int n = ntile * 16 + (lane & 15);
      int k = kstep * 32 + ((lane >> 4) & 3) * 8 + j;
      int g = n >> 8, jj = n & 255;
      const float* W = selW(g, Wf, Wi, Wg_, Wo);
      wxt[x] = (f16)W[k * 256 + jj];
      continue;
    }
    x -= 262144;
    if (x < 196608) {                 // in_proj frag-major (N=768)
      int j = x & 7, lane = (x >> 3) & 63, kstep = (x >> 9) & 7, ntile = x >> 12;
      int n = ntile * 16 + (lane & 15);
      int k = kstep * 32 + ((lane >> 4) & 3) * 8 + j;
      inpj[x] = (f16)inpw[k * 768 + n];
      continue;
    }
    x -= 196608;
    if (x < 65536) {                  // out_proj frag-major (N=256)
      int j = x & 7, lane = (x >> 3) & 63, kstep = (x >> 9) & 7, ntile = x >> 12;
      int n = ntile * 16 + (lane & 15);
      int k = kstep * 32 + ((lane >> 4) & 3) * 8 + j;
      outpj[x] = (f16)outpw[k * 256 + n];
      continue;
    }
    x -= 65536;
    {                                 // bias4
      int g = x >> 8, j = x & 255;
      const float* bp = selW(g, bf, bi, bg_, bo);
      bias4[x] = bp[j];
    }
  }
}

// ---------------------------------------------------------------------------
__global__ void cvt_x_k(const float4v* __restrict__ X, half4v* __restrict__ Xh)
{
  int i = blockIdx.x * 256 + threadIdx.x;   // grid sized exactly: 16777216/4
  float4v v = X[i];
  half4v h;
  h.x = (f16)v.x; h.y = (f16)v.y; h.z = (f16)v.z; h.w = (f16)v.w;
  Xh[i] = h;
}

// ---------------------------------------------------------------------------
// Generic MFMA GEMM: C[65536][NTOT] = A[65536][256](f16) @ Bfrag(N=NTOT,K=256)
// + bias[n].  OUT_EPI=false: store f16 to Oh.  OUT_EPI=true: Of += (f32).
// Block 256 thr (4 waves, 2x2 wave grid), tile 128x128, K chunks of 64.
// ---------------------------------------------------------------------------
template<int NTOT, bool OUT_EPI>
__global__ __launch_bounds__(256, 2) void gemm_k(const f16* __restrict__ A,
    const f16* __restrict__ Bf, const float* __restrict__ bias,
    f16* __restrict__ Oh, float* __restrict__ Of)
{
  __shared__ f16 Al[8192];            // [8 mtiles][2 ksteps][64 lanes][8]
  const int tid = threadIdx.x;
  const int lane = tid & 63;
  const int wm = (tid >> 7) & 1;
  const int wn = (tid >> 6) & 1;
  const int m0 = blockIdx.y * 128, n0 = blockIdx.x * 128;

  float4v acc[4][4];
  #pragma unroll
  for (int i = 0; i < 4; ++i)
    #pragma unroll
    for (int j = 0; j < 4; ++j) { acc[i][j].x = 0.f; acc[i][j].y = 0.f; acc[i][j].z = 0.f; acc[i][j].w = 0.f; }

  #pragma unroll 1
  for (int kc = 0; kc < 4; ++kc) {
    __syncthreads();
    #pragma unroll
    for (int p = 0; p < 4; ++p) {
      int m = p * 32 + (tid >> 3);
      int kk = (tid & 7) * 8;
      half8v v = *(const half8v*)(A + (size_t)(m0 + m) * 256 + kc * 64 + kk);
      int lt = ((kk >> 3) & 3) * 16 + (m & 15);
      *(half8v*)(Al + (((m >> 4) * 2 + (kk >> 5)) * 64 + lt) * 8) = v;
    }
    __syncthreads();
    half8v bfr[4][2], afr[4][2];
    #pragma unroll
    for (int i = 0; i < 4; ++i) {
      int NT = (n0 >> 4) + wn * 4 + i;
      #pragma unroll
      for (int ks = 0; ks < 2; ++ks)
        bfr[i][ks] = *(const half8v*)(Bf + (size_t)((NT * 8 + kc * 2 + ks) * 64 + lane) * 8);
    }
    #pragma unroll
    for (int i = 0; i < 4; ++i) {
      int MT = wm * 4 + i;
      #pragma unroll
      for (int ks = 0; ks < 2; ++ks)
        afr[i][ks] = *(const half8v*)(Al + ((MT * 2 + ks) * 64 + lane) * 8);
    }
    #pragma unroll
    for (int ks = 0; ks < 2; ++ks)
      #pragma unroll
      for (int i = 0; i < 4; ++i)
        #pragma unroll
        for (int jn = 0; jn < 4; ++jn)
          acc[i][jn] = __builtin_amdgcn_mfma_f32_16x16x32_f16(afr[i][ks], bfr[jn][ks], acc[i][jn], 0, 0, 0);
  }

  const int r0 = (lane >> 4) * 4, cn = lane & 15;
  #pragma unroll
  for (int i = 0; i < 4; ++i) {
    #pragma unroll
    for (int jn = 0; jn < 4; ++jn) {
      int n = n0 + wn * 64 + jn * 16 + cn;
      float bv = bias[n];
      int mb = m0 + wm * 64 + i * 16 + r0;
      #pragma unroll
      for (int r = 0; r < 4; ++r) {
        float v = acc[i][jn][r] + bv;
        size_t off = (size_t)(mb + r) * NTOT + n;
        if constexpr (OUT_EPI) Of[off] = v + Of[off];
        else                   Oh[off] = (f16)v;
      }
    }
  }
}

// ---------------------------------------------------------------------------
// LSTM scan. 64 WGs (one per batch element) x 512 threads (8 waves, 2/SIMD).
// thread t owns gate-columns c0=2t, c0+1 (same gate: g = t>>7).
// Recurrent weights (256 k-rows x 1024 cols f16): rows 0..191 in VGPRs
// (192 regs/thread of packed f16x2 — fits the 256-reg cap of (512,1), all
// architectural VGPRs, no AGPR moves, no spill), rows 192..255 in LDS (128KB).
// Per step: dots (hx from LDS broadcast b128, 4 indep acc chains) -> nonlin ->
// gates to LDS -> LDS-only barrier -> owners (t<256) update cx/hx, write Hseq
// f32 + f16 (stores stay in flight) -> LDS-only barrier. Xp prefetched 1 ahead.
// ---------------------------------------------------------------------------
__global__ __launch_bounds__(512, 1) void scan_k(const f16* __restrict__ Xp,
    const f16* __restrict__ Wscan, float* __restrict__ dout, f16* __restrict__ Hh)
{
  extern __shared__ unsigned smem[];
  unsigned* wtl = smem;                        // [32 r2][1024 c] u32 (f16x2)
  f16* hxs = (f16*)(smem + 32768);             // [256]
  float* gts = (float*)(smem + 32768 + 128);   // [1024]
  const int tid = threadIdx.x;
  const int b = blockIdx.x;
  const int c0 = tid << 1;
  const unsigned* W32 = (const unsigned*)Wscan;   // [1024 c][128 k-pairs]

  unsigned wv[192];
  #pragma unroll
  for (int r = 0; r < 96; ++r) {
    wv[r]      = W32[c0 * 128 + r];
    wv[96 + r] = W32[(c0 + 1) * 128 + r];
  }
  for (int e = tid; e < 32768; e += 512) {     // rows 192..255 -> LDS [r2][c]
    int r2 = e >> 10, c = e & 1023;
    wtl[(r2 << 10) + c] = W32[c * 128 + 96 + r2];
  }
  if (tid < 128) ((unsigned*)hxs)[tid] = 0u;
  float cx = 0.0f, hx_keep = 0.0f;
  const int gate = tid >> 7;
  __syncthreads();                             // prologue: full barrier is fine

  // Xp word for this (b, tid): stride between steps is 64*512 u32 = 1<<15.
  const unsigned* xptr = (const unsigned*)Xp + (size_t)b * 512 + tid;
  unsigned xp_cur = xptr[0];

  #pragma unroll 1
  for (int t = 0; t < 1024; ++t) {
    // Prefetch next step's x-projection; latency hides under this step's dots.
    unsigned xp_nxt = 0u;
    if (t + 1 < 1024) xp_nxt = xptr[(size_t)(t + 1) << 15];

    // 4 independent accumulator chains: col0 -> a0x/a0y, col1 -> a1x/a1y.
    // Issue order per z-group gives dep distance 4 instrs (covers VOP3P lat).
    float a0x = 0.0f, a0y = 0.0f, a1x = 0.0f, a1y = 0.0f;
    #pragma unroll
    for (int ch = 0; ch < 24; ++ch) {          // VGPR rows 0..191
      half8v h8 = *(const half8v*)(hxs + ch * 8);
      const half2v* hp = (const half2v*)&h8;
      int r = ch * 4;
      a0x = __builtin_amdgcn_fdot2(hp[0], u2h(wv[r + 0]), a0x, false);
      a1x = __builtin_amdgcn_fdot2(hp[0], u2h(wv[96 + r + 0]), a1x, false);
      a0y = __builtin_amdgcn_fdot2(hp[1], u2h(wv[r + 1]), a0y, false);
      a1y = __builtin_amdgcn_fdot2(hp[1], u2h(wv[96 + r + 1]), a1y, false);
      a0x = __builtin_amdgcn_fdot2(hp[2], u2h(wv[r + 2]), a0x, false);
      a1x = __builtin_amdgcn_fdot2(hp[2], u2h(wv[96 + r + 2]), a1x, false);
      a0y = __builtin_amdgcn_fdot2(hp[3], u2h(wv[r + 3]), a0y, false);
      a1y = __builtin_amdgcn_fdot2(hp[3], u2h(wv[96 + r + 3]), a1y, false);
    }
    #pragma unroll
    for (int ch = 0; ch < 8; ++ch) {           // LDS rows 192..255
      half8v h8 = *(const half8v*)(hxs + 192 + ch * 8);
      const half2v* hp = (const half2v*)&h8;
      #pragma unroll
      for (int z = 0; z < 4; z += 2) {
        int r2a = ch * 4 + z, r2b = ch * 4 + z + 1;
        uint2 wwa = *(const uint2*)(wtl + (r2a << 10) + c0);
        uint2 wwb = *(const uint2*)(wtl + (r2b << 10) + c0);
        a0x = __builtin_amdgcn_fdot2(hp[z],     u2h(wwa.x), a0x, false);
        a1x = __builtin_amdgcn_fdot2(hp[z],     u2h(wwa.y), a1x, false);
        a0y = __builtin_amdgcn_fdot2(hp[z + 1], u2h(wwb.x), a0y, false);
        a1y = __builtin_amdgcn_fdot2(hp[z + 1], u2h(wwb.y), a1y, false);
      }
    }
    half2v xph = u2h(xp_cur);
    float p0 = (a0x + a0y) + (float)xph.x;
    float p1 = (a1x + a1y) + (float)xph.y;
    float v0, v1;
    if (gate == 2) { v0 = tanh_fast(p0); v1 = tanh_fast(p1); }
    else           { v0 = sigm(p0);      v1 = sigm(p1); }
    float2v gv; gv.x = v0; gv.y = v1;
    *(float2v*)(gts + c0) = gv;
    wg_barrier_lds();                          // gts visible; no vmcnt drain
    if (tid < 256) {
      float fg = gts[tid], ig = gts[256 + tid], gg = gts[512 + tid], og = gts[768 + tid];
      cx = fg * cx + ig * gg;
      float hv = og * tanh_fast(cx);
      hx_keep = hv;
      hxs[tid] = (f16)hv;
      size_t off = (size_t)(t * 64 + b) * 256 + tid;
      dout[off] = hv;                          // stores stay in flight
      Hh[off] = (f16)hv;
    }
    wg_barrier_lds();                          // hxs visible; no vmcnt drain
    xp_cur = xp_nxt;
  }
  if (tid < 256) {
    dout[(size_t)16777216 + b * 256 + tid] = hx_keep;           // hx
    dout[(size_t)16777216 + 16384 + b * 256 + tid] = cx;        // cx
  }
}

// ---------------------------------------------------------------------------
// Fused batch-axis attention, one WG per (s, head). scores = q.k^T/8 over the
// B=64 axis, softmax, ctx = attn.v. f16 dot2, f32 accum, unnormalized-P trick.
// ---------------------------------------------------------------------------
__global__ __launch_bounds__(256, 2) void attn_k(const f16* __restrict__ qkv,
                                                 f16* __restrict__ ctx)
{
  __shared__ f16 ql[64 * 72];
  __shared__ f16 kl[64 * 72];
  __shared__ f16 vT[64 * 72];     // transposed: [d][k_b]
  __shared__ f16 at[64 * 72];     // exp'd scores (unnormalized), [q_b][k_b]
  __shared__ float sc[64 * 69];
  __shared__ float pmx[256], psm[256], rmx[64], rsm[64];
  const int tid = threadIdx.x;
  const int s = blockIdx.x >> 2, h = blockIdx.x & 3;
  {
    const int bb = tid >> 2, i = tid & 3;
    const f16* base = qkv + (size_t)(s * 64 + bb) * 768 + h * 64 + i * 16;
    half8v q0 = *(const half8v*)(base);
    half8v q1 = *(const half8v*)(base + 8);
    *(half8v*)(ql + bb * 72 + i * 16)     = q0;
    *(half8v*)(ql + bb * 72 + i * 16 + 8) = q1;
    half8v k0 = *(const half8v*)(base + 256);
    half8v k1 = *(const half8v*)(base + 264);
    *(half8v*)(kl + bb * 72 + i * 16)     = k0;
    *(half8v*)(kl + bb * 72 + i * 16 + 8) = k1;
    half8v v0 = *(const half8v*)(base + 512);
    half8v v1 = *(const half8v*)(base + 520);
    #pragma unroll
    for (int z = 0; z < 8; ++z) {
      vT[(i * 16 + z) * 72 + bb]     = v0[z];
      vT[(i * 16 + 8 + z) * 72 + bb] = v1[z];
    }
  }
  __syncthreads();
  {
    const int qb = tid >> 2, g = tid & 3;
    half8v qr[8];
    #pragma unroll
    for (int i = 0; i < 8; ++i) qr[i] = *(const half8v*)(ql + qb * 72 + i * 8);
    #pragma unroll 1
    for (int jj = 0; jj < 16; ++jj) {
      int kb = g + jj * 4;
      float a = 0.0f;
      #pragma unroll
      for (int i = 0; i < 8; ++i) {
        half8v kr = *(const half8v*)(kl + kb * 72 + i * 8);
        const half2v* kp = (const half2v*)&kr;
        const half2v* qp = (const half2v*)&qr[i];
        #pragma unroll
        for (int z = 0; z < 4; ++z) a = __builtin_amdgcn_fdot2(qp[z], kp[z], a, false);
      }
      sc[qb * 69 + kb] = a * 0.125f;
    }
  }
  __syncthreads();
  {
    const int r = tid & 63, q = tid >> 6;
    float m = -1e30f;
    #pragma unroll
    for (int z = 0; z < 16; ++z) m = fmaxf(m, sc[r * 69 + q * 16 + z]);
    pmx[q * 64 + r] = m;
  }
  __syncthreads();
  if (tid < 64)
    rmx[tid] = fmaxf(fmaxf(pmx[tid], pmx[64 + tid]), fmaxf(pmx[128 + tid], pmx[192 + tid]));
  __syncthreads();
  {
    const int r = tid & 63, q = tid >> 6;
    float mx = rmx[r], ssum = 0.0f;
    #pragma unroll
    for (int z = 0; z < 16; ++z) {
      float e = __expf(sc[r * 69 + q * 16 + z] - mx);
      ssum += e;
      at[r * 72 + q * 16 + z] = (f16)e;
    }
    psm[q * 64 + r] = ssum;
  }
  __syncthreads();
  if (tid < 64)
    rsm[tid] = (psm[tid] + psm[64 + tid]) + (psm[128 + tid] + psm[192 + tid]);
  __syncthreads();
  {
    const int qb = tid >> 2, g = tid & 3;
    half8v ar[8];
    #pragma unroll
    for (int i = 0; i < 8; ++i) ar[i] = *(const half8v*)(at + qb * 72 + i * 8);
    const float rinv = 1.0f / rsm[qb];
    f16* outp = ctx + (size_t)(s * 64 + qb) * 256 + h * 64;
    #pragma unroll 1
    for (int z = 0; z < 16; ++z) {
      int d = g + z * 4;
      float a = 0.0f;
      #pragma unroll
      for (int i = 0; i < 8; ++i) {
        half8v vr = *(const half8v*)(vT + d * 72 + i * 8);
        const half2v* vp = (const half2v*)&vr;
        const half2v* ap = (const half2v*)&ar[i];
        #pragma unroll
        for (int zz = 0; zz < 4; ++zz) a = __builtin_amdgcn_fdot2(ap[zz], vp[zz], a, false);
      }
      outp[d] = (f16)(a * rinv);
    }
  }
}

// ---------------------------------------------------------------------------
extern "C" void kernel_launch(void* const* d_in, const int* in_sizes, int n_in,
                              void* d_out, int out_size, void* d_ws, size_t ws_size,
                              hipStream_t stream)
{
  (void)in_sizes; (void)n_in; (void)out_size; (void)ws_size;
  const float* X    = (const float*)d_in[0];
  const float* Wf   = (const float*)d_in[1];
  const float* bf   = (const float*)d_in[2];
  const float* Wi   = (const float*)d_in[3];
  const float* bi   = (const float*)d_in[4];
  const float* Wg   = (const float*)d_in[5];
  const float* bg   = (const float*)d_in[6];
  const float* Wo   = (const float*)d_in[7];
  const float* bo   = (const float*)d_in[8];
  const float* inpw = (const float*)d_in[9];
  const float* inpb = (const float*)d_in[10];
  const float* outpw= (const float*)d_in[11];
  const float* outpb= (const float*)d_in[12];

  char* ws = (char*)d_ws;
  f16*   Xp    = (f16*)(ws + 0);
  f16*   qkv   = (f16*)(ws + 0);                 // reuses Xp region after scan
  f16*   ctxh  = (f16*)(ws + 100663296);         // also inside old Xp region
  f16*   Xh    = (f16*)(ws + 134217728);
  f16*   Hh    = (f16*)(ws + 167772160);
  f16*   wscan = (f16*)(ws + 201326592);
  f16*   wxt   = (f16*)(ws + 201850880);
  f16*   inpj  = (f16*)(ws + 202375168);
  f16*   outpj = (f16*)(ws + 202768384);
  float* bias4 = (float*)(ws + 202899456);
  float* out   = (float*)d_out;

  prep_k<<<1024, 256, 0, stream>>>(Wf, Wi, Wg, Wo, bf, bi, bg, bo, inpw, outpw,
                                   wscan, wxt, inpj, outpj, bias4);
  cvt_x_k<<<16384, 256, 0, stream>>>((const float4v*)X, (half4v*)Xh);
  gemm_k<1024, false><<<dim3(8, 512), 256, 0, stream>>>(Xh, wxt, bias4, Xp, nullptr);
  scan_k<<<64, 512, 135680, stream>>>(Xp, wscan, out, Hh);
  gemm_k<768, false><<<dim3(6, 512), 256, 0, stream>>>(Hh, inpj, inpb, qkv, nullptr);
  attn_k<<<4096, 256, 0, stream>>>(qkv, ctxh);
  gemm_k<256, true><<<dim3(2, 512), 256, 0, stream>>>(ctxh, outpj, outpb, nullptr, out);
}